// Round 6
// baseline (1854.780 us; speedup 1.0000x reference)
//
#include <hip/hip_runtime.h>

#define TPB 256
#define EPS_CAND 1e-3f

// ---------------- workspace layout (bytes) ----------------
// gp     u64 [128*900]       @ 0         921600
// widx   u32 [128*900]       @ 921600    460800
// dgrid  f32 [128*900]       @ 1382400   460800
// gmax32 u32 [128*900]       @ 1843200   460800   fp32-key cell max
// cnt    u32                 @ 2304000   1024
// wT     f32 [16*25*4*32*8]  @ 2305024   1638400  fwd weights [j][t][g][ci][c8]
// wTb    f32 [...]           @ 3943424   1638400  bwd weights (tap-flip, ch-swap)
// clist  u32 [2M]            @ 5581824   8388608  candidate gids (dead before CNN)
// acts   f32 [128*17*64*32]  @ 5581824   17825792 activations [b][l][pix][ch] (overlaps clist)
// total ~23.4 MB

static __device__ __forceinline__ unsigned long long dkey(double d) {
  unsigned long long b = (unsigned long long)__double_as_longlong(d);
  return (b & 0x8000000000000000ull) ? ~b : (b | 0x8000000000000000ull);
}
static __device__ __forceinline__ unsigned int key32(float f) {
  unsigned int b = __float_as_uint(f);
  return (b & 0x80000000u) ? ~b : (b | 0x80000000u);
}
static __device__ __forceinline__ float dec32(unsigned int k) {
  return __uint_as_float((k & 0x80000000u) ? (k & 0x7FFFFFFFu) : ~k);
}

// Fast deterministic fp64 expm1 (~2e-13 rel err); identical in all fp64 kernels.
static __device__ __forceinline__ double expm1_fast(double z) {
  double t = z * 1.4426950408889634;
  double k = rint(t);
  double r = fma(k, -6.9314718036912381649e-01, z);
  r = fma(k, -1.9082149292705877e-10, r);
  double p = 2.08767569878681e-09;
  p = fma(p, r, 2.505210838544172e-08);
  p = fma(p, r, 2.755731922398589e-07);
  p = fma(p, r, 2.7557319223985893e-06);
  p = fma(p, r, 2.48015873015873e-05);
  p = fma(p, r, 1.984126984126984e-04);
  p = fma(p, r, 1.388888888888889e-03);
  p = fma(p, r, 8.333333333333333e-03);
  p = fma(p, r, 4.1666666666666664e-02);
  p = fma(p, r, 1.6666666666666666e-01);
  p = fma(p, r, 5e-01);
  double q = fma(r * p, r, r);
  long long ki = (long long)k;
  double s = __longlong_as_double((unsigned long long)(1023LL + ki) << 52);
  return fma(s, q, s - 1.0);
}

static __device__ __forceinline__ void mlp_forward(
    float px, float py, float at,
    const float* __restrict__ W1, const float* __restrict__ b1,
    const float* __restrict__ W2, const float* __restrict__ b2,
    const float* __restrict__ W3, const float* __restrict__ b3,
    int& c0, int& c1, double& dx, double& dy, double& dist,
    double a1[16], double a2[16], double f[4]) {
  c0 = (int)floorf(px); c0 = c0 < 0 ? 0 : (c0 > 14 ? 14 : c0);
  c1 = (int)floorf(py); c1 = c1 < 0 ? 0 : (c1 > 14 ? 14 : c1);
  dx = (double)px - ((double)c0 + 0.5);
  dy = (double)py - ((double)c1 + 0.5);
  dist = sqrt(fma(dx, dx, fma(dy, dy, 1e-12)));
  double datt = (double)at;
#pragma unroll
  for (int j = 0; j < 16; ++j) {
    double z = fma(dist, (double)W1[j], fma(datt, (double)W1[16 + j], (double)b1[j]));
    a1[j] = z > 0.0 ? z : expm1_fast(z);
  }
#pragma unroll
  for (int j = 0; j < 16; ++j) {
    double z = (double)b2[j];
#pragma unroll
    for (int i = 0; i < 16; ++i) z = fma(a1[i], (double)W2[i * 16 + j], z);
    a2[j] = z > 0.0 ? z : expm1_fast(z);
  }
#pragma unroll
  for (int k = 0; k < 4; ++k) {
    double ff = (double)b3[k];
#pragma unroll
    for (int i = 0; i < 16; ++i) ff = fma(a2[i], (double)W3[i * 4 + k], ff);
    f[k] = ff;
  }
}

// fp32 twin: explicit fmaf everywhere -> bit-identical between k_pf32 and k_cand.
static __device__ __forceinline__ void mlp32(
    float px, float py, float at,
    const float* __restrict__ W1, const float* __restrict__ b1,
    const float* __restrict__ W2, const float* __restrict__ b2,
    const float* __restrict__ W3, const float* __restrict__ b3,
    int& c0, int& c1, float f[4]) {
  c0 = (int)floorf(px); c0 = c0 < 0 ? 0 : (c0 > 14 ? 14 : c0);
  c1 = (int)floorf(py); c1 = c1 < 0 ? 0 : (c1 > 14 ? 14 : c1);
  float dx = px - ((float)c0 + 0.5f);
  float dy = py - ((float)c1 + 0.5f);
  float dist = sqrtf(fmaf(dx, dx, fmaf(dy, dy, 1e-12f)));
  float a1[16], a2[16];
#pragma unroll
  for (int j = 0; j < 16; ++j) {
    float z = fmaf(dist, W1[j], fmaf(at, W1[16 + j], b1[j]));
    a1[j] = z > 0.f ? z : expm1f(z);
  }
#pragma unroll
  for (int j = 0; j < 16; ++j) {
    float z = b2[j];
#pragma unroll
    for (int i = 0; i < 16; ++i) z = fmaf(a1[i], W2[i * 16 + j], z);
    a2[j] = z > 0.f ? z : expm1f(z);
  }
#pragma unroll
  for (int k = 0; k < 4; ++k) {
    float ff = b3[k];
#pragma unroll
    for (int i = 0; i < 16; ++i) ff = fmaf(a2[i], W3[i * 4 + k], ff);
    f[k] = ff;
  }
}

__global__ __launch_bounds__(TPB)
void k_init(unsigned long long* __restrict__ gp, unsigned int* __restrict__ widx,
            unsigned int* __restrict__ gmax32, unsigned int* __restrict__ cnt) {
  int e = blockIdx.x * TPB + threadIdx.x;
  if (e < 128 * 900) {
    gp[e] = 0x8000000000000000ull;   // dkey(+0.0) -> scatter-max vs initial 0
    widx[e] = 0xFFFFFFFFu;
    gmax32[e] = 0x80000000u;         // key32(+0.0f)
  }
  if (e == 0) cnt[0] = 0;
}

// wT[(((j*25+t)*4+g)*32+ci)*8+c]  = cw[j][co=g*8+c][ci][t]
// wTb[(((j*25+t)*4+g)*32+co)*8+c] = cw[j][co][ci=g*8+c][24-t]
__global__ __launch_bounds__(TPB)
void k_wtrans(const float* __restrict__ cw, float* __restrict__ wT, float* __restrict__ wTb) {
  int i = blockIdx.x * TPB + threadIdx.x;
  if (i >= 409600) return;
  int c = i & 7;
  int m = (i >> 3) & 31;
  int g = (i >> 8) & 3;
  int jt = i >> 10;
  int t = jt % 25;
  int j = jt / 25;
  wT[i]  = cw[((size_t)(j * 32 + (g * 8 + c)) * 32 + m) * 25 + t];
  wTb[i] = cw[((size_t)(j * 32 + m) * 32 + (g * 8 + c)) * 25 + (24 - t)];
}

__global__ __launch_bounds__(TPB)
void k_pf32(const float* __restrict__ points, const float* __restrict__ attrs,
            const float* __restrict__ W1, const float* __restrict__ b1,
            const float* __restrict__ W2, const float* __restrict__ b2,
            const float* __restrict__ W3, const float* __restrict__ b3,
            unsigned int* __restrict__ gmax32) {
  int gid = blockIdx.x * TPB + threadIdx.x;
  float2 p2 = ((const float2*)points)[gid];
  float at = attrs[gid];
  int c0, c1; float f[4];
  mlp32(p2.x, p2.y, at, W1, b1, W2, b2, W3, b3, c0, c1, f);
  int b = gid >> 14;
  size_t base = (size_t)b * 900 + (size_t)(c0 * 15 + c1) * 4;
#pragma unroll
  for (int k = 0; k < 4; ++k) atomicMax(&gmax32[base + k], key32(f[k]));
}

__global__ __launch_bounds__(TPB)
void k_cand(const float* __restrict__ points, const float* __restrict__ attrs,
            const float* __restrict__ W1, const float* __restrict__ b1,
            const float* __restrict__ W2, const float* __restrict__ b2,
            const float* __restrict__ W3, const float* __restrict__ b3,
            const unsigned int* __restrict__ gmax32,
            unsigned int* __restrict__ clist, unsigned int* __restrict__ cnt) {
  int gid = blockIdx.x * TPB + threadIdx.x;
  float2 p2 = ((const float2*)points)[gid];
  float at = attrs[gid];
  int c0, c1; float f[4];
  mlp32(p2.x, p2.y, at, W1, b1, W2, b2, W3, b3, c0, c1, f);
  int b = gid >> 14;
  size_t base = (size_t)b * 900 + (size_t)(c0 * 15 + c1) * 4;
  bool cand = false;
#pragma unroll
  for (int k = 0; k < 4; ++k)
    cand |= (f[k] >= dec32(gmax32[base + k]) - EPS_CAND);
  if (cand) {
    unsigned pos = atomicAdd(cnt, 1u);
    clist[pos] = (unsigned)gid;
  }
}

__global__ __launch_bounds__(TPB)
void k_pf64(const float* __restrict__ points, const float* __restrict__ attrs,
            const float* __restrict__ W1, const float* __restrict__ b1,
            const float* __restrict__ W2, const float* __restrict__ b2,
            const float* __restrict__ W3, const float* __restrict__ b3,
            const unsigned int* __restrict__ clist, const unsigned int* __restrict__ cnt,
            unsigned long long* __restrict__ gp) {
  int n = (int)cnt[0];
  for (int i = blockIdx.x * TPB + threadIdx.x; i < n; i += gridDim.x * TPB) {
    int gid = (int)clist[i];
    float2 p2 = ((const float2*)points)[gid];
    float at = attrs[gid];
    int c0, c1; double dx, dy, dist, a1[16], a2[16], f[4];
    mlp_forward(p2.x, p2.y, at, W1, b1, W2, b2, W3, b3, c0, c1, dx, dy, dist, a1, a2, f);
    int b = gid >> 14;
    size_t base = (size_t)b * 900 + (size_t)(c0 * 15 + c1) * 4;
#pragma unroll
    for (int k = 0; k < 4; ++k) atomicMax(&gp[base + k], dkey(f[k]));
  }
}

__global__ __launch_bounds__(TPB)
void k_claim64(const float* __restrict__ points, const float* __restrict__ attrs,
               const float* __restrict__ W1, const float* __restrict__ b1,
               const float* __restrict__ W2, const float* __restrict__ b2,
               const float* __restrict__ W3, const float* __restrict__ b3,
               const unsigned int* __restrict__ clist, const unsigned int* __restrict__ cnt,
               const unsigned long long* __restrict__ gp, unsigned int* __restrict__ widx) {
  int n = (int)cnt[0];
  for (int i = blockIdx.x * TPB + threadIdx.x; i < n; i += gridDim.x * TPB) {
    int gid = (int)clist[i];
    float2 p2 = ((const float2*)points)[gid];
    float at = attrs[gid];
    int c0, c1; double dx, dy, dist, a1[16], a2[16], f[4];
    mlp_forward(p2.x, p2.y, at, W1, b1, W2, b2, W3, b3, c0, c1, dx, dy, dist, a1, a2, f);
    int b = gid >> 14;
    size_t base = (size_t)b * 900 + (size_t)(c0 * 15 + c1) * 4;
#pragma unroll
    for (int k = 0; k < 4; ++k)
      if (dkey(f[k]) == gp[base + k]) atomicMin(&widx[base + k], (unsigned)(gid & 16383));
  }
}

// 25-tap quarter conv: per tap 2 x ds_read_b128 (8 in-ch) + 64 fma (8 out-ch).
static __device__ __forceinline__ void conv_mac8(const float* __restrict__ Rd, int rd_base,
                                                 const float* __restrict__ wb, float acc[8]) {
  int po = rd_base;
  const float* wp = wb;
#pragma unroll 1
  for (int ky = 0; ky < 5; ++ky) {
#pragma unroll 1
    for (int kx = 0; kx < 5; ++kx) {
      const float4 a0 = *(const float4*)&Rd[po];
      const float4 a1 = *(const float4*)&Rd[po + 4];
#pragma unroll
      for (int c = 0; c < 8; ++c) {
        acc[c] = fmaf(wp[c],      a0.x, acc[c]);
        acc[c] = fmaf(wp[8 + c],  a0.y, acc[c]);
        acc[c] = fmaf(wp[16 + c], a0.z, acc[c]);
        acc[c] = fmaf(wp[24 + c], a0.w, acc[c]);
        acc[c] = fmaf(wp[32 + c], a1.x, acc[c]);
        acc[c] = fmaf(wp[40 + c], a1.y, acc[c]);
        acc[c] = fmaf(wp[48 + c], a1.z, acc[c]);
        acc[c] = fmaf(wp[56 + c], a1.w, acc[c]);
      }
      po += 36; wp += 1024;
    }
    po += 7 * 36;
  }
}

__global__ __launch_bounds__(1024, 4)
void k_cnn_fwd(const unsigned long long* __restrict__ gp,
               const float* __restrict__ c1w, const float* __restrict__ c1b,
               const float* __restrict__ bn1g, const float* __restrict__ bn1b,
               const float* __restrict__ wT, const float* __restrict__ cb,
               const float* __restrict__ bg, const float* __restrict__ bb,
               float* __restrict__ acts) {
  __shared__ float xin[900];
  __shared__ __align__(16) float bufA[5184], bufB[5184];  // [12x12 pix][36]
  __shared__ __align__(16) float4 partA[768], partB[768];
  const int tid = threadIdx.x;
  const int b = blockIdx.x;
  for (int t = tid; t < 5184; t += 1024) { bufA[t] = 0.f; bufB[t] = 0.f; }
  if (tid < 900) {
    int c = tid / 225, rem = tid - c * 225;
    unsigned long long k = gp[(size_t)b * 900 + rem * 4 + c];
    long long bits = (k & 0x8000000000000000ull) ? (long long)(k & 0x7FFFFFFFFFFFFFFFull)
                                                 : ~(long long)k;
    xin[c * 225 + rem] = (float)__longlong_as_double(bits);
  }
  __syncthreads();
  const float irs = 1.0f / sqrtf(1.0f + 1e-5f);
  float* actE = acts + (size_t)b * 34816;
#pragma unroll
  for (int r = 0; r < 2; ++r) {
    int k = tid + r * 1024;
    int co = k >> 6, pix = k & 63, y = pix >> 3, x = pix & 7;
    float acc = c1b[co];
    for (int ci = 0; ci < 4; ++ci)
#pragma unroll
      for (int ky = 0; ky < 5; ++ky) {
        int iy = 2 * y + ky - 2;
        if (iy < 0 || iy > 14) continue;
#pragma unroll
        for (int kx = 0; kx < 5; ++kx) {
          int ix = 2 * x + kx - 2;
          if (ix < 0 || ix > 14) continue;
          acc = fmaf(c1w[((co * 4 + ci) * 5 + ky) * 5 + kx], xin[ci * 225 + iy * 15 + ix], acc);
        }
      }
    float z = fmaf(acc, bn1g[co] * irs, bn1b[co]);
    float a = z > 0.f ? z : expm1f(z);
    bufA[((y + 2) * 12 + (x + 2)) * 36 + co] = a;
    actE[pix * 32 + co] = a;
  }
  __syncthreads();
  const int w = __builtin_amdgcn_readfirstlane(tid >> 6);
  const int lane = tid & 63;
  const int g = w & 3, q = w >> 2;
  const int y = lane >> 3, x = lane & 7;
  const int rd_base = (y * 12 + x) * 36 + q * 8;
  const int st_pix = ((y + 2) * 12 + (x + 2)) * 36 + g * 8;
#pragma unroll 1
  for (int j = 0; j < 16; ++j) {
    const float* Rd = (j & 1) ? bufB : bufA;
    float* Wr = (j & 1) ? bufA : bufB;
    const float* wb = wT + (size_t)j * 25600 + g * 256 + q * 64;
    float acc[8] = {0.f, 0.f, 0.f, 0.f, 0.f, 0.f, 0.f, 0.f};
    conv_mac8(Rd, rd_base, wb, acc);
    if (q > 0) {
      int slot = ((q - 1) * 4 + g) * 64 + lane;
      partA[slot] = make_float4(acc[0], acc[1], acc[2], acc[3]);
      partB[slot] = make_float4(acc[4], acc[5], acc[6], acc[7]);
    }
    __syncthreads();
    if (q == 0) {
#pragma unroll
      for (int p = 0; p < 3; ++p) {
        float4 pa = partA[(p * 4 + g) * 64 + lane];
        float4 pb = partB[(p * 4 + g) * 64 + lane];
        acc[0] += pa.x; acc[1] += pa.y; acc[2] += pa.z; acc[3] += pa.w;
        acc[4] += pb.x; acc[5] += pb.y; acc[6] += pb.z; acc[7] += pb.w;
      }
      const int cbase = j * 32 + g * 8;
      float av[8];
#pragma unroll
      for (int c = 0; c < 8; ++c) {
        float z = fmaf(acc[c] + cb[cbase + c], bg[cbase + c] * irs, bb[cbase + c]);
        av[c] = z > 0.f ? z : expm1f(z);
      }
      *(float4*)&Wr[st_pix]     = make_float4(av[0], av[1], av[2], av[3]);
      *(float4*)&Wr[st_pix + 4] = make_float4(av[4], av[5], av[6], av[7]);
      float* ap = actE + (size_t)(j + 1) * 2048 + lane * 32 + g * 8;
      *(float4*)&ap[0] = make_float4(av[0], av[1], av[2], av[3]);
      *(float4*)&ap[4] = make_float4(av[4], av[5], av[6], av[7]);
    }
    __syncthreads();
  }
}

__global__ __launch_bounds__(1024, 4)
void k_cnn_bwd(const float* __restrict__ acts,
               const float* __restrict__ wTb, const float* __restrict__ bg,
               const float* __restrict__ c1w, const float* __restrict__ bn1g,
               float* __restrict__ dgrid) {
  __shared__ __align__(16) float bufA[5184], bufB[5184];
  __shared__ __align__(16) float4 partA[768], partB[768];
  const int tid = threadIdx.x;
  const int b = blockIdx.x;
  for (int t = tid; t < 5184; t += 1024) { bufA[t] = 0.f; bufB[t] = 0.f; }
  __syncthreads();
  const float irs = 1.0f / sqrtf(1.0f + 1e-5f);
  const float* actE = acts + (size_t)b * 34816;
#pragma unroll
  for (int r = 0; r < 2; ++r) {
    int t = tid + r * 1024;
    int ch = t & 31, pix = t >> 5;
    float a = actE[16 * 2048 + pix * 32 + ch];
    float d = (a > 0.f ? 1.f : a + 1.f) * (bg[15 * 32 + ch] * irs);
    bufA[((2 + (pix >> 3)) * 12 + 2 + (pix & 7)) * 36 + ch] = d * (1.0f / 2048.0f);
  }
  __syncthreads();
  const int w = __builtin_amdgcn_readfirstlane(tid >> 6);
  const int lane = tid & 63;
  const int g = w & 3, q = w >> 2;
  const int y = lane >> 3, x = lane & 7;
  const int rd_base = (y * 12 + x) * 36 + q * 8;
  const int st_pix = ((y + 2) * 12 + (x + 2)) * 36 + g * 8;
#pragma unroll 1
  for (int jj = 0; jj < 16; ++jj) {
    const int j = 15 - jj;
    const float* Gb = (jj & 1) ? bufB : bufA;
    float* Wr = (jj & 1) ? bufA : bufB;
    const float* wb = wTb + (size_t)j * 25600 + g * 256 + q * 64;
    float acc[8] = {0.f, 0.f, 0.f, 0.f, 0.f, 0.f, 0.f, 0.f};
    conv_mac8(Gb, rd_base, wb, acc);
    if (q > 0) {
      int slot = ((q - 1) * 4 + g) * 64 + lane;
      partA[slot] = make_float4(acc[0], acc[1], acc[2], acc[3]);
      partB[slot] = make_float4(acc[4], acc[5], acc[6], acc[7]);
    }
    __syncthreads();
    if (q == 0) {
#pragma unroll
      for (int p = 0; p < 3; ++p) {
        float4 pa = partA[(p * 4 + g) * 64 + lane];
        float4 pb = partB[(p * 4 + g) * 64 + lane];
        acc[0] += pa.x; acc[1] += pa.y; acc[2] += pa.z; acc[3] += pa.w;
        acc[4] += pb.x; acc[5] += pb.y; acc[6] += pb.z; acc[7] += pb.w;
      }
      const float* ap = actE + (size_t)j * 2048 + lane * 32 + g * 8;
      float4 A0 = *(const float4*)&ap[0];
      float4 A1 = *(const float4*)&ap[4];
      float avv[8] = {A0.x, A0.y, A0.z, A0.w, A1.x, A1.y, A1.z, A1.w};
#pragma unroll
      for (int c = 0; c < 8; ++c) {
        float s = (j > 0) ? bg[(j - 1) * 32 + g * 8 + c] : bn1g[g * 8 + c];
        acc[c] *= (avv[c] > 0.f ? 1.f : avv[c] + 1.f) * (s * irs);
      }
      *(float4*)&Wr[st_pix]     = make_float4(acc[0], acc[1], acc[2], acc[3]);
      *(float4*)&Wr[st_pix + 4] = make_float4(acc[4], acc[5], acc[6], acc[7]);
    }
    __syncthreads();
  }
  if (tid < 900) {
    int cid = tid >> 2, ci = tid & 3;
    int u = cid / 15, v = cid - u * 15;
    float acc = 0.f;
    for (int co = 0; co < 32; ++co) {
      const float* wp = c1w + (co * 4 + ci) * 25;
#pragma unroll
      for (int ky = 0; ky < 5; ++ky) {
        int t2 = u + 2 - ky;
        if (t2 < 0 || t2 > 14 || (t2 & 1)) continue;
        int yy = t2 >> 1;
#pragma unroll
        for (int kx = 0; kx < 5; ++kx) {
          int s2 = v + 2 - kx;
          if (s2 < 0 || s2 > 14 || (s2 & 1)) continue;
          int xq = s2 >> 1;
          acc = fmaf(wp[ky * 5 + kx], bufA[((yy + 2) * 12 + (xq + 2)) * 36 + co], acc);
        }
      }
    }
    dgrid[(size_t)b * 900 + tid] = acc;
  }
}

__global__ __launch_bounds__(TPB)
void k_winner(const float* __restrict__ points, const float* __restrict__ attrs,
              const float* __restrict__ W1, const float* __restrict__ b1,
              const float* __restrict__ W2, const float* __restrict__ b2,
              const float* __restrict__ W3, const float* __restrict__ b3,
              const unsigned int* __restrict__ widx, const float* __restrict__ dgrid,
              float* __restrict__ dpoints, float* __restrict__ dattrs) {
  int e = blockIdx.x * TPB + threadIdx.x;  // 115200
  unsigned pi = widx[e];
  if (pi == 0xFFFFFFFFu) return;
  float g = dgrid[e];
  if (g == 0.f) return;
  int b = e / 900;
  int r = e - b * 900;
  int ch = r & 3;
  size_t pidx = ((size_t)b << 14) + pi;
  float px = points[2 * pidx], py = points[2 * pidx + 1], at = attrs[pidx];
  int c0, c1; double dx, dy, dist, a1[16], a2[16], f[4];
  mlp_forward(px, py, at, W1, b1, W2, b2, W3, b3, c0, c1, dx, dy, dist, a1, a2, f);
  double gz2[16];
#pragma unroll
  for (int i = 0; i < 16; ++i) {
    double ga2 = (double)g * (double)W3[i * 4 + ch];
    gz2[i] = ga2 * (a2[i] > 0.0 ? 1.0 : a2[i] + 1.0);
  }
  double gd = 0.0, gatt = 0.0;
#pragma unroll
  for (int i = 0; i < 16; ++i) {
    double ga1 = 0.0;
#pragma unroll
    for (int jj = 0; jj < 16; ++jj) ga1 = fma(gz2[jj], (double)W2[i * 16 + jj], ga1);
    double gz1 = ga1 * (a1[i] > 0.0 ? 1.0 : a1[i] + 1.0);
    gd = fma(gz1, (double)W1[i], gd);
    gatt = fma(gz1, (double)W1[16 + i], gatt);
  }
  double inv = 1.0 / dist;
  atomicAdd(&dpoints[2 * pidx], (float)(gd * dx * inv));
  atomicAdd(&dpoints[2 * pidx + 1], (float)(gd * dy * inv));
  atomicAdd(&dattrs[pidx], (float)gatt);
}

__global__ __launch_bounds__(TPB)
void k_reduce(const float* __restrict__ dpoints, const float* __restrict__ dattrs,
              const float* __restrict__ gforce, const float* __restrict__ gattr,
              float* __restrict__ out) {
  int i = blockIdx.x * TPB + threadIdx.x;
  float dp0 = dpoints[2 * i], dp1 = dpoints[2 * i + 1], da = dattrs[i];
  float gf0 = gforce[2 * i], gf1 = gforce[2 * i + 1], ga = gattr[i];
  float e0 = dp0 - gf0, e1 = dp1 - gf1, e2 = da - ga;
  float c1v = e0 * e0 + e1 * e1;
  float c2v = e2 * e2;
  float sm = dp0 + dp1 + da;
  float ab = fabsf(dp0) + fabsf(dp1) + fabsf(da);
#pragma unroll
  for (int o = 32; o > 0; o >>= 1) {
    c1v += __shfl_down(c1v, o, 64);
    c2v += __shfl_down(c2v, o, 64);
    sm += __shfl_down(sm, o, 64);
    ab += __shfl_down(ab, o, 64);
  }
  __shared__ float red[4][4];
  int wv = threadIdx.x >> 6, ln = threadIdx.x & 63;
  if (ln == 0) { red[wv][0] = c1v; red[wv][1] = c2v; red[wv][2] = sm; red[wv][3] = ab; }
  __syncthreads();
  if (threadIdx.x == 0) {
    float C1 = 0, C2 = 0, S = 0, A = 0;
    for (int w = 0; w < 4; ++w) { C1 += red[w][0]; C2 += red[w][1]; S += red[w][2]; A += red[w][3]; }
    atomicAdd(&out[0], C1 * (1.0f / 4194304.0f) + C2 * (1.0f / 2097152.0f));
    atomicAdd(&out[1], S * (1.0f / 128.0f));
    atomicAdd(&out[2], A * (1.0f / 128.0f));
  }
}

extern "C" void kernel_launch(void* const* d_in, const int* in_sizes, int n_in,
                              void* d_out, int out_size, void* d_ws, size_t ws_size,
                              hipStream_t stream) {
  (void)in_sizes; (void)n_in; (void)ws_size;
  const float* points = (const float*)d_in[0];
  const float* attrs  = (const float*)d_in[1];
  const float* gforce = (const float*)d_in[2];
  const float* gattr  = (const float*)d_in[3];
  const float* W1 = (const float*)d_in[4];
  const float* b1 = (const float*)d_in[5];
  const float* W2 = (const float*)d_in[6];
  const float* b2 = (const float*)d_in[7];
  const float* W3 = (const float*)d_in[8];
  const float* b3 = (const float*)d_in[9];
  const float* c1w  = (const float*)d_in[10];
  const float* c1b  = (const float*)d_in[11];
  const float* bn1g = (const float*)d_in[12];
  const float* bn1b = (const float*)d_in[13];
  const float* cw = (const float*)d_in[14];
  const float* cb = (const float*)d_in[15];
  const float* bg = (const float*)d_in[16];
  const float* bb = (const float*)d_in[17];
  float* out = (float*)d_out;

  char* ws = (char*)d_ws;
  unsigned long long* gp = (unsigned long long*)(ws);
  unsigned int* widx = (unsigned int*)(ws + 921600);
  float* dgrid = (float*)(ws + 1382400);
  unsigned int* gmax32 = (unsigned int*)(ws + 1843200);
  unsigned int* cnt = (unsigned int*)(ws + 2304000);
  float* wT  = (float*)(ws + 2305024);
  float* wTb = (float*)(ws + 3943424);
  unsigned int* clist = (unsigned int*)(ws + 5581824);  // dead before acts is written
  float* acts = (float*)(ws + 5581824);

  float* dpoints = out + 3;
  float* dattrs  = out + 3 + 4194304;

  hipMemsetAsync(d_out, 0, (size_t)out_size * sizeof(float), stream);
  k_init<<<450, TPB, 0, stream>>>(gp, widx, gmax32, cnt);
  k_wtrans<<<1600, TPB, 0, stream>>>(cw, wT, wTb);
  k_pf32<<<8192, TPB, 0, stream>>>(points, attrs, W1, b1, W2, b2, W3, b3, gmax32);
  k_cand<<<8192, TPB, 0, stream>>>(points, attrs, W1, b1, W2, b2, W3, b3, gmax32, clist, cnt);
  k_pf64<<<2048, TPB, 0, stream>>>(points, attrs, W1, b1, W2, b2, W3, b3, clist, cnt, gp);
  k_claim64<<<2048, TPB, 0, stream>>>(points, attrs, W1, b1, W2, b2, W3, b3, clist, cnt, gp, widx);
  k_cnn_fwd<<<128, 1024, 0, stream>>>(gp, c1w, c1b, bn1g, bn1b, wT, cb, bg, bb, acts);
  k_cnn_bwd<<<128, 1024, 0, stream>>>(acts, wTb, bg, c1w, bn1g, dgrid);
  k_winner<<<450, TPB, 0, stream>>>(points, attrs, W1, b1, W2, b2, W3, b3, widx, dgrid,
                                    dpoints, dattrs);
  k_reduce<<<8192, TPB, 0, stream>>>(dpoints, dattrs, gforce, gattr, out);
}

// Round 7
// 1211.792 us; speedup vs baseline: 1.5306x; 1.5306x over previous
//
#include <hip/hip_runtime.h>

#define TPB 256

// ---------------- workspace layout (bytes) ----------------
// gp    u64 [128*900]       @ 0         921600   packed: key50 | (16383-idx)
// dgrid f32 [128*900]       @ 921600    460800
// wT    f32 [16*25*4*32*8]  @ 1382400   1638400  fwd weights [j][t][g][ci][c8]
// wTb   f32 [...]           @ 3020800   1638400  bwd weights (tap-flip, ch-swap)
// acts  f32 [128*17*64*32]  @ 4659200   17825792 activations [b][l][pix][ch]
// total ~22.5 MB

static __device__ __forceinline__ unsigned long long dkey(double d) {
  unsigned long long b = (unsigned long long)__double_as_longlong(d);
  return (b & 0x8000000000000000ull) ? ~b : (b | 0x8000000000000000ull);
}

// Fast deterministic fp64 expm1 (~2e-13 rel err).
static __device__ __forceinline__ double expm1_fast(double z) {
  double t = z * 1.4426950408889634;
  double k = rint(t);
  double r = fma(k, -6.9314718036912381649e-01, z);
  r = fma(k, -1.9082149292705877e-10, r);
  double p = 2.08767569878681e-09;
  p = fma(p, r, 2.505210838544172e-08);
  p = fma(p, r, 2.755731922398589e-07);
  p = fma(p, r, 2.7557319223985893e-06);
  p = fma(p, r, 2.48015873015873e-05);
  p = fma(p, r, 1.984126984126984e-04);
  p = fma(p, r, 1.388888888888889e-03);
  p = fma(p, r, 8.333333333333333e-03);
  p = fma(p, r, 4.1666666666666664e-02);
  p = fma(p, r, 1.6666666666666666e-01);
  p = fma(p, r, 5e-01);
  double q = fma(r * p, r, r);
  long long ki = (long long)k;
  double s = __longlong_as_double((unsigned long long)(1023LL + ki) << 52);
  return fma(s, q, s - 1.0);
}

static __device__ __forceinline__ void mlp_forward(
    float px, float py, float at,
    const float* __restrict__ W1, const float* __restrict__ b1,
    const float* __restrict__ W2, const float* __restrict__ b2,
    const float* __restrict__ W3, const float* __restrict__ b3,
    int& c0, int& c1, double& dx, double& dy, double& dist,
    double a1[16], double a2[16], double f[4]) {
  c0 = (int)floorf(px); c0 = c0 < 0 ? 0 : (c0 > 14 ? 14 : c0);
  c1 = (int)floorf(py); c1 = c1 < 0 ? 0 : (c1 > 14 ? 14 : c1);
  dx = (double)px - ((double)c0 + 0.5);
  dy = (double)py - ((double)c1 + 0.5);
  dist = sqrt(fma(dx, dx, fma(dy, dy, 1e-12)));
  double datt = (double)at;
#pragma unroll
  for (int j = 0; j < 16; ++j) {
    double z = fma(dist, (double)W1[j], fma(datt, (double)W1[16 + j], (double)b1[j]));
    a1[j] = z > 0.0 ? z : expm1_fast(z);
  }
#pragma unroll
  for (int j = 0; j < 16; ++j) {
    double z = (double)b2[j];
#pragma unroll
    for (int i = 0; i < 16; ++i) z = fma(a1[i], (double)W2[i * 16 + j], z);
    a2[j] = z > 0.0 ? z : expm1_fast(z);
  }
#pragma unroll
  for (int k = 0; k < 4; ++k) {
    double ff = (double)b3[k];
#pragma unroll
    for (int i = 0; i < 16; ++i) ff = fma(a2[i], (double)W3[i * 4 + k], ff);
    f[k] = ff;
  }
}

__global__ __launch_bounds__(TPB)
void k_init(unsigned long long* __restrict__ gp) {
  int e = blockIdx.x * TPB + threadIdx.x;
  if (e < 128 * 900) gp[e] = 0x8000000000000000ull;  // dkey(+0.0), idx-field 0
}

// wT[(((j*25+t)*4+g)*32+ci)*8+c]  = cw[j][co=g*8+c][ci][t]
// wTb[(((j*25+t)*4+g)*32+co)*8+c] = cw[j][co][ci=g*8+c][24-t]
__global__ __launch_bounds__(TPB)
void k_wtrans(const float* __restrict__ cw, float* __restrict__ wT, float* __restrict__ wTb) {
  int i = blockIdx.x * TPB + threadIdx.x;
  if (i >= 409600) return;
  int c = i & 7;
  int m = (i >> 3) & 31;
  int g = (i >> 8) & 3;
  int jt = i >> 10;
  int t = jt % 25;
  int j = jt / 25;
  wT[i]  = cw[((size_t)(j * 32 + (g * 8 + c)) * 32 + m) * 25 + t];
  wTb[i] = cw[((size_t)(j * 32 + m) * 32 + (g * 8 + c)) * 25 + (24 - t)];
}

// Single fused scatter-max + winner-claim pass: atomicMax on
// packed = (dkey(f) & ~0x3FFF) | (16383 - local_idx).
// Primary order: 50-bit fp64 key prefix; tie-break: lowest point index.
__global__ __launch_bounds__(TPB)
void k_scatter(const float* __restrict__ points, const float* __restrict__ attrs,
               const float* __restrict__ W1, const float* __restrict__ b1,
               const float* __restrict__ W2, const float* __restrict__ b2,
               const float* __restrict__ W3, const float* __restrict__ b3,
               unsigned long long* __restrict__ gp) {
  int gid = blockIdx.x * TPB + threadIdx.x;  // exactly 2^21 threads
  float2 p2 = ((const float2*)points)[gid];
  float at = attrs[gid];
  int c0, c1; double dx, dy, dist, a1[16], a2[16], f[4];
  mlp_forward(p2.x, p2.y, at, W1, b1, W2, b2, W3, b3, c0, c1, dx, dy, dist, a1, a2, f);
  int b = gid >> 14;
  unsigned long long inv = (unsigned long long)(16383 - (gid & 16383));
  size_t base = (size_t)b * 900 + (size_t)(c0 * 15 + c1) * 4;
#pragma unroll
  for (int k = 0; k < 4; ++k)
    atomicMax(&gp[base + k], (dkey(f[k]) & 0xFFFFFFFFFFFFC000ull) | inv);
}

// 25-tap quarter conv: per tap 2 x ds_read_b128 (8 in-ch) + 64 fma (8 out-ch).
static __device__ __forceinline__ void conv_mac8(const float* __restrict__ Rd, int rd_base,
                                                 const float* __restrict__ wb, float acc[8]) {
  int po = rd_base;
  const float* wp = wb;
#pragma unroll 1
  for (int ky = 0; ky < 5; ++ky) {
#pragma unroll 1
    for (int kx = 0; kx < 5; ++kx) {
      const float4 a0 = *(const float4*)&Rd[po];
      const float4 a1 = *(const float4*)&Rd[po + 4];
#pragma unroll
      for (int c = 0; c < 8; ++c) {
        acc[c] = fmaf(wp[c],      a0.x, acc[c]);
        acc[c] = fmaf(wp[8 + c],  a0.y, acc[c]);
        acc[c] = fmaf(wp[16 + c], a0.z, acc[c]);
        acc[c] = fmaf(wp[24 + c], a0.w, acc[c]);
        acc[c] = fmaf(wp[32 + c], a1.x, acc[c]);
        acc[c] = fmaf(wp[40 + c], a1.y, acc[c]);
        acc[c] = fmaf(wp[48 + c], a1.z, acc[c]);
        acc[c] = fmaf(wp[56 + c], a1.w, acc[c]);
      }
      po += 36; wp += 1024;
    }
    po += 7 * 36;
  }
}

// Fused CNN forward + backward, one block per example.
__global__ __launch_bounds__(1024, 4)
void k_cnn(const unsigned long long* __restrict__ gp,
           const float* __restrict__ c1w, const float* __restrict__ c1b,
           const float* __restrict__ bn1g, const float* __restrict__ bn1b,
           const float* __restrict__ wT, const float* __restrict__ wTb,
           const float* __restrict__ cb, const float* __restrict__ bg,
           const float* __restrict__ bb,
           float* __restrict__ acts, float* __restrict__ dgrid) {
  __shared__ float xin[900];
  __shared__ __align__(16) float bufA[5184], bufB[5184];  // [12x12 pix][36]
  __shared__ __align__(16) float4 partA[768], partB[768];
  const int tid = threadIdx.x;
  const int b = blockIdx.x;
  for (int t = tid; t < 5184; t += 1024) { bufA[t] = 0.f; bufB[t] = 0.f; }
  if (tid < 900) {
    int c = tid / 225, rem = tid - c * 225;
    unsigned long long k = gp[(size_t)b * 900 + rem * 4 + c] & 0xFFFFFFFFFFFFC000ull;
    long long bits = (k & 0x8000000000000000ull) ? (long long)(k & 0x7FFFFFFFFFFFFFFFull)
                                                 : ~(long long)k;
    xin[c * 225 + rem] = (float)__longlong_as_double(bits);
  }
  __syncthreads();
  const float irs = 1.0f / sqrtf(1.0f + 1e-5f);
  float* actE = acts + (size_t)b * 34816;
  // ---- conv1: 4x15x15 -> 32x8x8, stride 2, pad 2 (2 outputs/thread) ----
#pragma unroll
  for (int r = 0; r < 2; ++r) {
    int k = tid + r * 1024;
    int co = k >> 6, pix = k & 63, y = pix >> 3, x = pix & 7;
    float acc = c1b[co];
    for (int ci = 0; ci < 4; ++ci)
#pragma unroll
      for (int ky = 0; ky < 5; ++ky) {
        int iy = 2 * y + ky - 2;
        if (iy < 0 || iy > 14) continue;
#pragma unroll
        for (int kx = 0; kx < 5; ++kx) {
          int ix = 2 * x + kx - 2;
          if (ix < 0 || ix > 14) continue;
          acc = fmaf(c1w[((co * 4 + ci) * 5 + ky) * 5 + kx], xin[ci * 225 + iy * 15 + ix], acc);
        }
      }
    float z = fmaf(acc, bn1g[co] * irs, bn1b[co]);
    float a = z > 0.f ? z : expm1f(z);
    bufA[((y + 2) * 12 + (x + 2)) * 36 + co] = a;
    actE[pix * 32 + co] = a;
  }
  __syncthreads();
  const int w = __builtin_amdgcn_readfirstlane(tid >> 6);
  const int lane = tid & 63;
  const int g = w & 3, q = w >> 2;
  const int y = lane >> 3, x = lane & 7;
  const int rd_base = (y * 12 + x) * 36 + q * 8;
  const int st_pix = ((y + 2) * 12 + (x + 2)) * 36 + g * 8;
  // ---- forward deep layers ----
#pragma unroll 1
  for (int j = 0; j < 16; ++j) {
    const float* Rd = (j & 1) ? bufB : bufA;
    float* Wr = (j & 1) ? bufA : bufB;
    const float* wb = wT + (size_t)j * 25600 + g * 256 + q * 64;
    float acc[8] = {0.f, 0.f, 0.f, 0.f, 0.f, 0.f, 0.f, 0.f};
    conv_mac8(Rd, rd_base, wb, acc);
    if (q > 0) {
      int slot = ((q - 1) * 4 + g) * 64 + lane;
      partA[slot] = make_float4(acc[0], acc[1], acc[2], acc[3]);
      partB[slot] = make_float4(acc[4], acc[5], acc[6], acc[7]);
    }
    __syncthreads();
    if (q == 0) {
#pragma unroll
      for (int p = 0; p < 3; ++p) {
        float4 pa = partA[(p * 4 + g) * 64 + lane];
        float4 pb = partB[(p * 4 + g) * 64 + lane];
        acc[0] += pa.x; acc[1] += pa.y; acc[2] += pa.z; acc[3] += pa.w;
        acc[4] += pb.x; acc[5] += pb.y; acc[6] += pb.z; acc[7] += pb.w;
      }
      const int cbase = j * 32 + g * 8;
      float av[8];
#pragma unroll
      for (int c = 0; c < 8; ++c) {
        float z = fmaf(acc[c] + cb[cbase + c], bg[cbase + c] * irs, bb[cbase + c]);
        av[c] = z > 0.f ? z : expm1f(z);
      }
      *(float4*)&Wr[st_pix]     = make_float4(av[0], av[1], av[2], av[3]);
      *(float4*)&Wr[st_pix + 4] = make_float4(av[4], av[5], av[6], av[7]);
      float* ap = actE + (size_t)(j + 1) * 2048 + lane * 32 + g * 8;
      *(float4*)&ap[0] = make_float4(av[0], av[1], av[2], av[3]);
      *(float4*)&ap[4] = make_float4(av[4], av[5], av[6], av[7]);
    }
    __syncthreads();
  }
  // ---- backward: init g_z15 (halos still zero; interiors fully overwritten) ----
#pragma unroll
  for (int r = 0; r < 2; ++r) {
    int t = tid + r * 1024;
    int ch = t & 31, pix = t >> 5;
    float a = actE[16 * 2048 + pix * 32 + ch];
    float d = (a > 0.f ? 1.f : a + 1.f) * (bg[15 * 32 + ch] * irs);
    bufA[((2 + (pix >> 3)) * 12 + 2 + (pix & 7)) * 36 + ch] = d * (1.0f / 2048.0f);
  }
  __syncthreads();
#pragma unroll 1
  for (int jj = 0; jj < 16; ++jj) {
    const int j = 15 - jj;
    const float* Gb = (jj & 1) ? bufB : bufA;
    float* Wr = (jj & 1) ? bufA : bufB;
    const float* wb = wTb + (size_t)j * 25600 + g * 256 + q * 64;
    float acc[8] = {0.f, 0.f, 0.f, 0.f, 0.f, 0.f, 0.f, 0.f};
    conv_mac8(Gb, rd_base, wb, acc);
    if (q > 0) {
      int slot = ((q - 1) * 4 + g) * 64 + lane;
      partA[slot] = make_float4(acc[0], acc[1], acc[2], acc[3]);
      partB[slot] = make_float4(acc[4], acc[5], acc[6], acc[7]);
    }
    __syncthreads();
    if (q == 0) {
#pragma unroll
      for (int p = 0; p < 3; ++p) {
        float4 pa = partA[(p * 4 + g) * 64 + lane];
        float4 pb = partB[(p * 4 + g) * 64 + lane];
        acc[0] += pa.x; acc[1] += pa.y; acc[2] += pa.z; acc[3] += pa.w;
        acc[4] += pb.x; acc[5] += pb.y; acc[6] += pb.z; acc[7] += pb.w;
      }
      const float* ap = actE + (size_t)j * 2048 + lane * 32 + g * 8;
      float4 A0 = *(const float4*)&ap[0];
      float4 A1 = *(const float4*)&ap[4];
      float avv[8] = {A0.x, A0.y, A0.z, A0.w, A1.x, A1.y, A1.z, A1.w};
#pragma unroll
      for (int c = 0; c < 8; ++c) {
        float s = (j > 0) ? bg[(j - 1) * 32 + g * 8 + c] : bn1g[g * 8 + c];
        acc[c] *= (avv[c] > 0.f ? 1.f : avv[c] + 1.f) * (s * irs);
      }
      *(float4*)&Wr[st_pix]     = make_float4(acc[0], acc[1], acc[2], acc[3]);
      *(float4*)&Wr[st_pix + 4] = make_float4(acc[4], acc[5], acc[6], acc[7]);
    }
    __syncthreads();
  }
  // bufA holds g_z0 (fully scaled); conv1 backward to the 4x15x15 grid input
  if (tid < 900) {
    int cid = tid >> 2, ci = tid & 3;
    int u = cid / 15, v = cid - u * 15;
    float acc = 0.f;
    for (int co = 0; co < 32; ++co) {
      const float* wp = c1w + (co * 4 + ci) * 25;
#pragma unroll
      for (int ky = 0; ky < 5; ++ky) {
        int t2 = u + 2 - ky;
        if (t2 < 0 || t2 > 14 || (t2 & 1)) continue;
        int yy = t2 >> 1;
#pragma unroll
        for (int kx = 0; kx < 5; ++kx) {
          int s2 = v + 2 - kx;
          if (s2 < 0 || s2 > 14 || (s2 & 1)) continue;
          int xq = s2 >> 1;
          acc = fmaf(wp[ky * 5 + kx], bufA[((yy + 2) * 12 + (xq + 2)) * 36 + co], acc);
        }
      }
    }
    dgrid[(size_t)b * 900 + tid] = acc;
  }
}

__global__ __launch_bounds__(TPB)
void k_winner(const float* __restrict__ points, const float* __restrict__ attrs,
              const float* __restrict__ W1, const float* __restrict__ b1,
              const float* __restrict__ W2, const float* __restrict__ b2,
              const float* __restrict__ W3, const float* __restrict__ b3,
              const unsigned long long* __restrict__ gp, const float* __restrict__ dgrid,
              float* __restrict__ dpoints, float* __restrict__ dattrs) {
  int e = blockIdx.x * TPB + threadIdx.x;  // 115200
  unsigned long long pk = gp[e];
  if (pk <= 0x8000000000000000ull) return;  // empty / never-beaten cell
  float g = dgrid[e];
  if (g == 0.f) return;
  int b = e / 900;
  int r = e - b * 900;
  int ch = r & 3;
  int pi = 16383 - (int)(pk & 0x3FFFull);
  size_t pidx = ((size_t)b << 14) + pi;
  float px = points[2 * pidx], py = points[2 * pidx + 1], at = attrs[pidx];
  int c0, c1; double dx, dy, dist, a1[16], a2[16], f[4];
  mlp_forward(px, py, at, W1, b1, W2, b2, W3, b3, c0, c1, dx, dy, dist, a1, a2, f);
  double gz2[16];
#pragma unroll
  for (int i = 0; i < 16; ++i) {
    double ga2 = (double)g * (double)W3[i * 4 + ch];
    gz2[i] = ga2 * (a2[i] > 0.0 ? 1.0 : a2[i] + 1.0);
  }
  double gd = 0.0, gatt = 0.0;
#pragma unroll
  for (int i = 0; i < 16; ++i) {
    double ga1 = 0.0;
#pragma unroll
    for (int jj = 0; jj < 16; ++jj) ga1 = fma(gz2[jj], (double)W2[i * 16 + jj], ga1);
    double gz1 = ga1 * (a1[i] > 0.0 ? 1.0 : a1[i] + 1.0);
    gd = fma(gz1, (double)W1[i], gd);
    gatt = fma(gz1, (double)W1[16 + i], gatt);
  }
  double inv = 1.0 / dist;
  atomicAdd(&dpoints[2 * pidx], (float)(gd * dx * inv));
  atomicAdd(&dpoints[2 * pidx + 1], (float)(gd * dy * inv));
  atomicAdd(&dattrs[pidx], (float)gatt);
}

__global__ __launch_bounds__(TPB)
void k_reduce(const float* __restrict__ dpoints, const float* __restrict__ dattrs,
              const float* __restrict__ gforce, const float* __restrict__ gattr,
              float* __restrict__ out) {
  int i = blockIdx.x * TPB + threadIdx.x;
  float dp0 = dpoints[2 * i], dp1 = dpoints[2 * i + 1], da = dattrs[i];
  float gf0 = gforce[2 * i], gf1 = gforce[2 * i + 1], ga = gattr[i];
  float e0 = dp0 - gf0, e1 = dp1 - gf1, e2 = da - ga;
  float c1v = e0 * e0 + e1 * e1;
  float c2v = e2 * e2;
  float sm = dp0 + dp1 + da;
  float ab = fabsf(dp0) + fabsf(dp1) + fabsf(da);
#pragma unroll
  for (int o = 32; o > 0; o >>= 1) {
    c1v += __shfl_down(c1v, o, 64);
    c2v += __shfl_down(c2v, o, 64);
    sm += __shfl_down(sm, o, 64);
    ab += __shfl_down(ab, o, 64);
  }
  __shared__ float red[4][4];
  int wv = threadIdx.x >> 6, ln = threadIdx.x & 63;
  if (ln == 0) { red[wv][0] = c1v; red[wv][1] = c2v; red[wv][2] = sm; red[wv][3] = ab; }
  __syncthreads();
  if (threadIdx.x == 0) {
    float C1 = 0, C2 = 0, S = 0, A = 0;
    for (int w = 0; w < 4; ++w) { C1 += red[w][0]; C2 += red[w][1]; S += red[w][2]; A += red[w][3]; }
    atomicAdd(&out[0], C1 * (1.0f / 4194304.0f) + C2 * (1.0f / 2097152.0f));
    atomicAdd(&out[1], S * (1.0f / 128.0f));
    atomicAdd(&out[2], A * (1.0f / 128.0f));
  }
}

extern "C" void kernel_launch(void* const* d_in, const int* in_sizes, int n_in,
                              void* d_out, int out_size, void* d_ws, size_t ws_size,
                              hipStream_t stream) {
  (void)in_sizes; (void)n_in; (void)ws_size;
  const float* points = (const float*)d_in[0];
  const float* attrs  = (const float*)d_in[1];
  const float* gforce = (const float*)d_in[2];
  const float* gattr  = (const float*)d_in[3];
  const float* W1 = (const float*)d_in[4];
  const float* b1 = (const float*)d_in[5];
  const float* W2 = (const float*)d_in[6];
  const float* b2 = (const float*)d_in[7];
  const float* W3 = (const float*)d_in[8];
  const float* b3 = (const float*)d_in[9];
  const float* c1w  = (const float*)d_in[10];
  const float* c1b  = (const float*)d_in[11];
  const float* bn1g = (const float*)d_in[12];
  const float* bn1b = (const float*)d_in[13];
  const float* cw = (const float*)d_in[14];
  const float* cb = (const float*)d_in[15];
  const float* bg = (const float*)d_in[16];
  const float* bb = (const float*)d_in[17];
  float* out = (float*)d_out;

  char* ws = (char*)d_ws;
  unsigned long long* gp = (unsigned long long*)(ws);
  float* dgrid = (float*)(ws + 921600);
  float* wT  = (float*)(ws + 1382400);
  float* wTb = (float*)(ws + 3020800);
  float* acts = (float*)(ws + 4659200);

  float* dpoints = out + 3;
  float* dattrs  = out + 3 + 4194304;

  hipMemsetAsync(d_out, 0, (size_t)out_size * sizeof(float), stream);
  k_init<<<450, TPB, 0, stream>>>(gp);
  k_wtrans<<<1600, TPB, 0, stream>>>(cw, wT, wTb);
  k_scatter<<<8192, TPB, 0, stream>>>(points, attrs, W1, b1, W2, b2, W3, b3, gp);
  k_cnn<<<128, 1024, 0, stream>>>(gp, c1w, c1b, bn1g, bn1b, wT, wTb, cb, bg, bb, acts, dgrid);
  k_winner<<<450, TPB, 0, stream>>>(points, attrs, W1, b1, W2, b2, W3, b3, gp, dgrid,
                                    dpoints, dattrs);
  k_reduce<<<8192, TPB, 0, stream>>>(dpoints, dattrs, gforce, gattr, out);
}